// Round 12
// baseline (187.911 us; speedup 1.0000x reference)
//
#include <hip/hip_runtime.h>
#include <hip/hip_fp16.h>

#define NN 50000
#define EE 800000
#define NBUCK 196   // dst buckets of 256 nodes each
#define CAP 5120    // per-bucket edge capacity (mean ~4082, sigma ~64 -> 16 sigma)
#define TILEA 2048
#define NBA ((EE + TILEA - 1) / TILEA)   // 391
#define NGB 782     // ceil(50000/64) row blocks for MFMA gemm1
#define SRCS_MAX (EE + 8 * NN + 64)      // padded CSR upper bound + slack
#define LOG2E 1.4426950408889634f

typedef _Float16 half8 __attribute__((ext_vector_type(8)));
typedef float floatx4 __attribute__((ext_vector_type(4)));
typedef float floatx2 __attribute__((ext_vector_type(2)));

// fp8 e4m3 (OCP) helpers — gfx950 native converts
__device__ __forceinline__ unsigned char f32_to_fp8(float a) {
    int r = __builtin_amdgcn_cvt_pk_fp8_f32(a, a, 0, false);
    return (unsigned char)(r & 0xff);
}
__device__ __forceinline__ float fp8_byte0_to_f32(unsigned v) {
    floatx2 r = __builtin_amdgcn_cvt_pk_f32_fp8(v, false);
    return r[0];
}
// ---- native transcendentals -----------------------------------------------------
__device__ __forceinline__ float fexp2(float x) {       // input pre-scaled by log2e
#if __has_builtin(__builtin_amdgcn_exp2f)
    return __builtin_amdgcn_exp2f(x);
#else
    return exp2f(x);
#endif
}
__device__ __forceinline__ float fexp(float x) {
    return fexp2(x * LOG2E);
}
__device__ __forceinline__ float flog(float x) {
#if __has_builtin(__builtin_amdgcn_logf)
    return 0.6931471805599453f * __builtin_amdgcn_logf(x);
#else
    return __logf(x);
#endif
}
__device__ __forceinline__ float frcp(float x) {
#if __has_builtin(__builtin_amdgcn_rcpf)
    return __builtin_amdgcn_rcpf(x);
#else
    return 1.f / x;
#endif
}

// ---------- prep: W1/W2 -> fp16 MFMA B-fragments; cursor; sentinel rows ---------
// pk1 record per node (128B): [8 x f32 al(head) | 64 x fp8 vals | 32B pad]
__global__ void k_prep(const float* __restrict__ W1, const float* __restrict__ W2,
                       _Float16* __restrict__ Bf1, _Float16* __restrict__ Bf2,
                       int* __restrict__ cursor, float* __restrict__ al2s,
                       unsigned char* __restrict__ pk1, __half* __restrict__ h2p) {
    int tid = blockIdx.x * 256 + threadIdx.x;
    if (tid < 1024) {
        int kk = tid >> 8, ct = (tid >> 6) & 3, L = tid & 63;
        int k0 = kk * 32 + (L >> 4) * 8, col = ct * 16 + (L & 15);
        half8 v;
        #pragma unroll
        for (int j = 0; j < 8; j++) v[j] = (_Float16)W1[(k0 + j) * 64 + col];
        *(half8*)(Bf1 + ((size_t)((kk * 4 + ct) * 64 + L)) * 8) = v;
    } else if (tid < 1024 + 384) {
        int u = tid - 1024;
        int kk = u / 192, rem = u % 192;
        int ct = rem >> 6, L = rem & 63;
        int k0 = kk * 32 + (L >> 4) * 8, col = ct * 16 + (L & 15);
        half8 v;
        #pragma unroll
        for (int j = 0; j < 8; j++)
            v[j] = (col < 40) ? (_Float16)W2[(k0 + j) * 40 + col] : (_Float16)0.f;
        *(half8*)(Bf2 + ((size_t)((kk * 3 + ct) * 64 + L)) * 8) = v;
    } else {
        int u = tid - 1408;
        if (u < NBUCK) cursor[u] = 0;
        if (u == 208) al2s[NN] = -1e30f;
        if (u >= 216 && u < 236) ((unsigned*)(h2p + (size_t)NN * 40))[u - 216] = 0u;
        if (u >= 240 && u < 264) {   // sentinel pk1 record: al=-1e30 (p=0), vals 0
            int dw = u - 240;
            ((float*)(pk1 + (size_t)NN * 128))[dw] = (dw < 8) ? -1e30f : 0.f;
        }
    }
}

// ---------- FUSED independent stage: blocks [0,NBA) bucketA, [NBA,NBA+NGB) gemm1
__global__ __launch_bounds__(256) void k_fusedAG(
    const int* __restrict__ ei, int* __restrict__ cursor,
    unsigned* __restrict__ bucketData,
    const float* __restrict__ x, const float* __restrict__ topo,
    const _Float16* __restrict__ Bf1,
    const float* __restrict__ a_src, const float* __restrict__ a_dst,
    unsigned char* __restrict__ pk1, float* __restrict__ aldst) {
    if (blockIdx.x < NBA) {
        __shared__ int cnt[NBUCK], base[NBUCK];
        int t = threadIdx.x;
        for (int i = t; i < NBUCK; i += 256) cnt[i] = 0;
        __syncthreads();
        int e0 = blockIdx.x * TILEA;
        int nE = min(TILEA, EE - e0);
        unsigned pk[8]; int bk[8], rk[8];
        int m = 0;
        for (int i = t; i < nE; i += 256) {
            int e = e0 + i;
            int s = ei[e], d = ei[EE + e];
            pk[m] = ((unsigned)d << 16) | (unsigned)s;
            bk[m] = d >> 8;
            rk[m] = atomicAdd(&cnt[bk[m]], 1);
            m++;
        }
        __syncthreads();
        for (int i = t; i < NBUCK; i += 256)
            base[i] = (cnt[i] > 0) ? atomicAdd(&cursor[i], cnt[i]) : 0;
        __syncthreads();
        for (int k = 0; k < m; k++) {
            int pos = base[bk[k]] + rk[k];
            if (pos < CAP) bucketData[(size_t)bk[k] * CAP + pos] = pk[k];
        }
        return;
    }
    // ---- gemm1: MFMA -> packed pk1 records (fp8 vals + fp32 logits) + aldst
    int wave = threadIdx.x >> 6, lane = threadIdx.x & 63;
    int row0 = (blockIdx.x - NBA) * 64 + wave * 16;
    if (row0 >= NN) return;
    int g = lane >> 4, li = lane & 15;
    int myrow = row0 + li;                        // A-operand row (m = lane&15)
    half8 B[16];
    const half8* bp = (const half8*)Bf1;
    #pragma unroll
    for (int i = 0; i < 16; i++) B[i] = bp[i * 64 + lane];
    floatx4 acc[4] = {{0,0,0,0},{0,0,0,0},{0,0,0,0},{0,0,0,0}};
    #pragma unroll
    for (int kk = 0; kk < 4; kk++) {
        int k0 = kk * 32 + g * 8;
        const float* sp = (k0 == 120) ? (topo + (size_t)myrow * 8)
                                      : (x + (size_t)myrow * 120 + k0);
        float4 u0 = ((const float4*)sp)[0];
        float4 u1 = ((const float4*)sp)[1];
        half8 av;
        av[0] = (_Float16)u0.x; av[1] = (_Float16)u0.y;
        av[2] = (_Float16)u0.z; av[3] = (_Float16)u0.w;
        av[4] = (_Float16)u1.x; av[5] = (_Float16)u1.y;
        av[6] = (_Float16)u1.z; av[7] = (_Float16)u1.w;
        #pragma unroll
        for (int ct = 0; ct < 4; ct++)
            acc[ct] = __builtin_amdgcn_mfma_f32_16x16x32_f16(av, B[kk * 4 + ct], acc[ct], 0, 0, 0);
    }
    // h1 values into packed records: byte = row*128 + 32 + col
    #pragma unroll
    for (int ct = 0; ct < 4; ct++)
        #pragma unroll
        for (int r = 0; r < 4; r++) {
            int col = ct * 16 + li;
            pk1[(size_t)(row0 + 4 * g + r) * 128 + 32 + col] = f32_to_fp8(acc[ct][r]);
        }
    // attention logits: head = 2*ct + (li>>3), dim = li&7 (heads are 8-col aligned)
    float ps[4][4], pd[4][4];
    #pragma unroll
    for (int ct = 0; ct < 4; ct++) {
        int head = 2 * ct + (li >> 3), dix = li & 7;
        float asv = a_src[head * 8 + dix];
        float adv = a_dst[head * 8 + dix];
        #pragma unroll
        for (int r = 0; r < 4; r++) {
            ps[ct][r] = acc[ct][r] * asv;
            pd[ct][r] = acc[ct][r] * adv;
        }
    }
    #pragma unroll
    for (int off = 1; off <= 4; off <<= 1)
        #pragma unroll
        for (int ct = 0; ct < 4; ct++)
            #pragma unroll
            for (int r = 0; r < 4; r++) {
                ps[ct][r] += __shfl_xor(ps[ct][r], off, 64);
                pd[ct][r] += __shfl_xor(pd[ct][r], off, 64);
            }
    if ((li & 7) == 0) {
        #pragma unroll
        for (int ct = 0; ct < 4; ct++) {
            int head = 2 * ct + (li >> 3);
            #pragma unroll
            for (int r = 0; r < 4; r++) {
                int row = row0 + 4 * g + r;
                *(float*)(pk1 + (size_t)row * 128 + head * 4) = ps[ct][r] * LOG2E;
                aldst[row * 8 + head] = pd[ct][r] * LOG2E;
            }
        }
    }
}

// ---------- Pass B (1024 threads): inline arena scan + per-bucket counting sort -
__global__ __launch_bounds__(1024) void k_bucketB(const unsigned* __restrict__ bucketData,
        const int* __restrict__ cursor,
        int2* __restrict__ rowseg, int* __restrict__ srcs) {
    __shared__ int cnt[256], cur[256], sbuf[256], svals[256];
    __shared__ int sorted[CAP + 2048];
    int b = blockIdx.x, t = threadIdx.x;
    int nloc = min(256, NN - b * 256);
    int ecnt = min(cursor[b], CAP);
    size_t inBase = (size_t)b * CAP;
    if (t < 256) {
        int vv = 0;
        if (t < NBUCK) {
            int nl = min(256, NN - t * 256);
            vv = min(cursor[t], CAP) + 8 * nl;
        }
        svals[t] = vv;
    }
    __syncthreads();
    int* a = svals; int* bb = sbuf;
    for (int off = 1; off < 256; off <<= 1) {
        if (t < 256) bb[t] = a[t] + ((t >= off) ? a[t - off] : 0);
        __syncthreads();
        int* tmp = a; a = bb; bb = tmp;
    }
    int outBase = (b == 0) ? 0 : a[b - 1];
    __syncthreads();
    if (t < 256) cnt[t] = (t < nloc) ? 1 : 0;
    __syncthreads();
    for (int i = t; i < ecnt; i += 1024) {
        unsigned u = bucketData[inBase + i];
        atomicAdd(&cnt[(u >> 16) & 255], 1);
    }
    __syncthreads();
    int cv = 0, pcv = 0;
    if (t < 256) {
        cv = cnt[t];
        pcv = (t < nloc) ? ((cv + 7) & ~7) : 0;
        sbuf[t] = pcv;
    }
    __syncthreads();
    a = sbuf; bb = cnt;
    for (int off = 1; off < 256; off <<= 1) {
        if (t < 256) bb[t] = a[t] + ((t >= off) ? a[t - off] : 0);
        __syncthreads();
        int* tmp = a; a = bb; bb = tmp;
    }
    int total = a[255];
    int excl = (t < 256) ? (a[t] - pcv) : 0;
    __syncthreads();
    if (t < nloc) {
        rowseg[b * 256 + t] = make_int2(outBase + excl, outBase + excl + pcv);
        sorted[excl] = b * 256 + t;              // self loop at slot 0 of segment
        for (int k = cv; k < pcv; k++) sorted[excl + k] = NN;  // sentinel pads
        cur[t] = excl + 1;
    }
    __syncthreads();
    for (int i = t; i < ecnt; i += 1024) {
        unsigned u = bucketData[inBase + i];
        int ld = (u >> 16) & 255;
        int p = atomicAdd(&cur[ld], 1);
        sorted[p] = (int)(u & 0xffffu);
    }
    __syncthreads();
    for (int i = t; i < total; i += 1024) srcs[outBase + i] = sorted[i];
}

// ------- layer 1 aggregation: wave=dst, LANE=COLUMN, sequential edge groups -----
__global__ __launch_bounds__(256) void k_agg1(
    const int2* __restrict__ rowseg, const int* __restrict__ srcs,
    const unsigned char* __restrict__ pk1, const float* __restrict__ aldst,
    const float* __restrict__ b1, __half* __restrict__ hout) {
    int wave = threadIdx.x >> 6;
    int lane = threadIdx.x & 63;
    int d = blockIdx.x * 4 + wave;
    if (d >= NN) return;
    int head = lane >> 3;                    // 8 cols per head
    unsigned alOff = (unsigned)head << 2;    // al_h at record + 4*head
    unsigned vOff = 32u + (unsigned)lane;    // val at record + 32 + col
    float adst = aldst[d * 8 + head];        // pre-scaled by log2e
    int2 seg = rowseg[d];
    int jb = __builtin_amdgcn_readfirstlane(seg.x);
    int je = __builtin_amdgcn_readfirstlane(seg.y);
    const int* sp = srcs + jb;
    int ng = (je - jb) >> 2;                 // groups of 4 edges; even, >= 2
    float c = 0.f, ssum = 0.f;
    int4 iA = *(const int4*)sp;
    float a0, a1, a2, a3; unsigned v0, v1, v2, v3;
    {
        const unsigned char* r0 = pk1 + ((size_t)(unsigned)iA.x << 7);
        const unsigned char* r1 = pk1 + ((size_t)(unsigned)iA.y << 7);
        const unsigned char* r2 = pk1 + ((size_t)(unsigned)iA.z << 7);
        const unsigned char* r3 = pk1 + ((size_t)(unsigned)iA.w << 7);
        a0 = *(const float*)(r0 + alOff); v0 = r0[vOff];
        a1 = *(const float*)(r1 + alOff); v1 = r1[vOff];
        a2 = *(const float*)(r2 + alOff); v2 = r2[vOff];
        a3 = *(const float*)(r3 + alOff); v3 = r3[vOff];
    }
    for (int g = 0; g < ng; g++) {
        int gn = (g + 1 < ng) ? g + 1 : g;   // last group reloads itself (harmless)
        int4 iB = *(const int4*)(sp + 4 * gn);
        const unsigned char* r0 = pk1 + ((size_t)(unsigned)iB.x << 7);
        const unsigned char* r1 = pk1 + ((size_t)(unsigned)iB.y << 7);
        const unsigned char* r2 = pk1 + ((size_t)(unsigned)iB.z << 7);
        const unsigned char* r3 = pk1 + ((size_t)(unsigned)iB.w << 7);
        float n0 = *(const float*)(r0 + alOff); unsigned w0 = r0[vOff];
        float n1 = *(const float*)(r1 + alOff); unsigned w1 = r1[vOff];
        float n2 = *(const float*)(r2 + alOff); unsigned w2 = r2[vOff];
        float n3 = *(const float*)(r3 + alOff); unsigned w3 = r3[vOff];
        float e, p;
        e = a0 + adst; p = fexp2(fmaxf(e, 0.2f * e)); ssum += p; c += p * fp8_byte0_to_f32(v0);
        e = a1 + adst; p = fexp2(fmaxf(e, 0.2f * e)); ssum += p; c += p * fp8_byte0_to_f32(v1);
        e = a2 + adst; p = fexp2(fmaxf(e, 0.2f * e)); ssum += p; c += p * fp8_byte0_to_f32(v2);
        e = a3 + adst; p = fexp2(fmaxf(e, 0.2f * e)); ssum += p; c += p * fp8_byte0_to_f32(v3);
        a0 = n0; a1 = n1; a2 = n2; a3 = n3;
        v0 = w0; v1 = w1; v2 = w2; v3 = w3;
    }
    // per-lane epilogue: ssum is this head's denominator (uniform within head group)
    float inv = frcp(ssum);
    float vo = c * inv + b1[lane];
    vo = (vo > 0.f) ? vo : (fexp(vo) - 1.f);   // ELU
    hout[(size_t)d * 64 + lane] = __float2half(vo);
}

// ------- layer 2 node GEMM via MFMA (h2p fp16, PACKED 40-col/80B rows) ----------
__global__ __launch_bounds__(256) void k_gemm2(
    const __half* __restrict__ hout, const _Float16* __restrict__ Bf2,
    const float* __restrict__ a_src2, const float* __restrict__ a_dst2,
    __half* __restrict__ h2p, float* __restrict__ al2s, float* __restrict__ al2d) {
    int wave = threadIdx.x >> 6, lane = threadIdx.x & 63;
    int row0 = blockIdx.x * 64 + wave * 16;
    if (row0 >= NN) return;
    int g = lane >> 4, li = lane & 15;
    int myrow = row0 + li;
    half8 B[6];
    const half8* bp = (const half8*)Bf2;
    #pragma unroll
    for (int i = 0; i < 6; i++) B[i] = bp[i * 64 + lane];
    floatx4 acc[3] = {{0,0,0,0},{0,0,0,0},{0,0,0,0}};
    #pragma unroll
    for (int kk = 0; kk < 2; kk++) {
        int k0 = kk * 32 + g * 8;
        half8 av = *(const half8*)(hout + (size_t)myrow * 64 + k0);
        #pragma unroll
        for (int ct = 0; ct < 3; ct++)
            acc[ct] = __builtin_amdgcn_mfma_f32_16x16x32_f16(av, B[kk * 3 + ct], acc[ct], 0, 0, 0);
    }
    float ts[4] = {0.f, 0.f, 0.f, 0.f}, td[4] = {0.f, 0.f, 0.f, 0.f};
    #pragma unroll
    for (int ct = 0; ct < 3; ct++) {
        int col = ct * 16 + li;
        bool ok = (col < 40);
        float asv = ok ? a_src2[col] : 0.f;
        float adv = ok ? a_dst2[col] : 0.f;
        #pragma unroll
        for (int r = 0; r < 4; r++) {
            ts[r] += acc[ct][r] * asv;
            td[r] += acc[ct][r] * adv;
            if (ok) h2p[(size_t)(row0 + 4 * g + r) * 40 + col] = __float2half(acc[ct][r]);
        }
    }
    #pragma unroll
    for (int off = 1; off <= 8; off <<= 1)
        #pragma unroll
        for (int r = 0; r < 4; r++) {
            ts[r] += __shfl_xor(ts[r], off, 64);
            td[r] += __shfl_xor(td[r], off, 64);
        }
    if (li == 0) {
        #pragma unroll
        for (int r = 0; r < 4; r++) {
            int row = row0 + 4 * g + r;
            al2s[row] = ts[r] * LOG2E;   // pre-scaled for exp2
            al2d[row] = td[r] * LOG2E;
        }
    }
}

// ------- layer 2 aggregation + log_softmax: wave=dst, LANE=COLUMN ---------------
__global__ __launch_bounds__(256) void k_agg2(
    const int2* __restrict__ rowseg, const int* __restrict__ srcs,
    const float* __restrict__ al2s, const float* __restrict__ al2d,
    const __half* __restrict__ h2p, const float* __restrict__ b2,
    float* __restrict__ out) {
    int wave = threadIdx.x >> 6;
    int lane = threadIdx.x & 63;
    int d = blockIdx.x * 4 + wave;
    if (d >= NN) return;
    bool act = (lane < 40);
    unsigned vOff = 2u * (unsigned)(act ? lane : 39);
    const char* H = (const char*)h2p;
    float adst = al2d[d];                    // pre-scaled by log2e
    int2 seg = rowseg[d];
    int jb = __builtin_amdgcn_readfirstlane(seg.x);
    int je = __builtin_amdgcn_readfirstlane(seg.y);
    const int* sp = srcs + jb;
    int ng = (je - jb) >> 2;
    float c = 0.f, ssum = 0.f;
    int4 iA = *(const int4*)sp;
    float a0, a1, a2, a3; unsigned short v0, v1, v2, v3;
    {
        a0 = al2s[iA.x]; v0 = *(const unsigned short*)(H + (unsigned)iA.x * 80u + vOff);
        a1 = al2s[iA.y]; v1 = *(const unsigned short*)(H + (unsigned)iA.y * 80u + vOff);
        a2 = al2s[iA.z]; v2 = *(const unsigned short*)(H + (unsigned)iA.z * 80u + vOff);
        a3 = al2s[iA.w]; v3 = *(const unsigned short*)(H + (unsigned)iA.w * 80u + vOff);
    }
    for (int g = 0; g < ng; g++) {
        int gn = (g + 1 < ng) ? g + 1 : g;
        int4 iB = *(const int4*)(sp + 4 * gn);
        float n0 = al2s[iB.x]; unsigned short w0 = *(const unsigned short*)(H + (unsigned)iB.x * 80u + vOff);
        float n1 = al2s[iB.y]; unsigned short w1 = *(const unsigned short*)(H + (unsigned)iB.y * 80u + vOff);
        float n2 = al2s[iB.z]; unsigned short w2 = *(const unsigned short*)(H + (unsigned)iB.z * 80u + vOff);
        float n3 = al2s[iB.w]; unsigned short w3 = *(const unsigned short*)(H + (unsigned)iB.w * 80u + vOff);
        float e, p;
        e = a0 + adst; p = fexp2(fmaxf(e, 0.2f * e)); ssum += p; c += p * __half2float(*(__half*)&v0);
        e = a1 + adst; p = fexp2(fmaxf(e, 0.2f * e)); ssum += p; c += p * __half2float(*(__half*)&v1);
        e = a2 + adst; p = fexp2(fmaxf(e, 0.2f * e)); ssum += p; c += p * __half2float(*(__half*)&v2);
        e = a3 + adst; p = fexp2(fmaxf(e, 0.2f * e)); ssum += p; c += p * __half2float(*(__half*)&v3);
        a0 = n0; a1 = n1; a2 = n2; a3 = n3;
        v0 = w0; v1 = w1; v2 = w2; v3 = w3;
    }
    float inv = frcp(ssum);
    float o = act ? (c * inv + b2[act ? lane : 0]) : -3.0e38f;
    float mo = o;
    #pragma unroll
    for (int off = 1; off <= 32; off <<= 1) mo = fmaxf(mo, __shfl_xor(mo, off, 64));
    float te = act ? fexp(o - mo) : 0.f;
    #pragma unroll
    for (int off = 1; off <= 32; off <<= 1) te += __shfl_xor(te, off, 64);
    float ls = mo + flog(te);
    if (act) out[(size_t)d * 40 + lane] = o - ls;
}

extern "C" void kernel_launch(void* const* d_in, const int* in_sizes, int n_in,
                              void* d_out, int out_size, void* d_ws, size_t ws_size,
                              hipStream_t stream) {
    (void)in_sizes; (void)n_in; (void)out_size; (void)ws_size;
    const float* x    = (const float*)d_in[0];
    const float* topo = (const float*)d_in[1];
    const int*   ei   = (const int*)d_in[2];
    const float* W1   = (const float*)d_in[3];
    const float* as1  = (const float*)d_in[4];
    const float* ad1  = (const float*)d_in[5];
    const float* b1   = (const float*)d_in[6];
    const float* W2   = (const float*)d_in[7];
    const float* as2  = (const float*)d_in[8];
    const float* ad2  = (const float*)d_in[9];
    const float* b2   = (const float*)d_in[10];
    float* out = (float*)d_out;

    char* ws = (char*)d_ws;
    size_t off = 0;
    auto alloc = [&](size_t bytes) {
        void* p = ws + off;
        off += (bytes + 255) / 256 * 256;
        return p;
    };
    int2*          rowseg     = (int2*)alloc((size_t)NN * 8);
    int*           cursor     = (int*)alloc(NBUCK * 4);
    unsigned*      bucketData = (unsigned*)alloc((size_t)NBUCK * CAP * 4);
    int*           srcs       = (int*)alloc((size_t)SRCS_MAX * 4);
    float*         aldst1     = (float*)alloc((size_t)NN * 8 * 4);
    float*         al2s       = (float*)alloc((NN + 1) * 4);
    float*         al2d       = (float*)alloc(NN * 4);
    _Float16*      Bf1        = (_Float16*)alloc(4 * 4 * 64 * 8 * 2);
    _Float16*      Bf2        = (_Float16*)alloc(2 * 3 * 64 * 8 * 2);
    unsigned char* pk1        = (unsigned char*)alloc((size_t)(NN + 1) * 128);
    __half*        hout       = (__half*)alloc((size_t)NN * 64 * 2);
    __half*        h2p        = (__half*)alloc((size_t)(NN + 1) * 40 * 2);

    k_prep    <<<7,         256,  0, stream>>>(W1, W2, Bf1, Bf2, cursor, al2s, pk1, h2p);
    k_fusedAG <<<NBA + NGB, 256,  0, stream>>>(ei, cursor, bucketData,
                                               x, topo, Bf1, as1, ad1, pk1, aldst1);
    k_bucketB <<<NBUCK,     1024, 0, stream>>>(bucketData, cursor, rowseg, srcs);
    k_agg1    <<<(NN + 3) / 4, 256, 0, stream>>>(rowseg, srcs, pk1, aldst1, b1, hout);
    k_gemm2   <<<782,       256,  0, stream>>>(hout, Bf2, as2, ad2, h2p, al2s, al2d);
    k_agg2    <<<(NN + 3) / 4, 256, 0, stream>>>(rowseg, srcs, al2s, al2d, h2p, b2, out);
}

// Round 13
// 171.671 us; speedup vs baseline: 1.0946x; 1.0946x over previous
//
#include <hip/hip_runtime.h>
#include <hip/hip_fp16.h>

#define NN 50000
#define EE 800000
#define NBUCK 196   // dst buckets of 256 nodes each
#define CAP 5120    // per-bucket edge capacity (mean ~4082, sigma ~64 -> 16 sigma)
#define TILEA 2048
#define NBA ((EE + TILEA - 1) / TILEA)   // 391
#define NGB 782     // ceil(50000/64) row blocks for MFMA gemm1
#define SRCS_MAX (EE + 8 * NN)           // padded CSR upper bound (1.2M)

typedef _Float16 half8 __attribute__((ext_vector_type(8)));
typedef float floatx4 __attribute__((ext_vector_type(4)));
typedef float floatx2 __attribute__((ext_vector_type(2)));

// fp8 e4m3 (OCP) helpers — gfx950 native converts
__device__ __forceinline__ unsigned char f32_to_fp8(float a) {
    int r = __builtin_amdgcn_cvt_pk_fp8_f32(a, a, 0, false);
    return (unsigned char)(r & 0xff);
}
__device__ __forceinline__ float2 fp8pair_lo(unsigned v) {
    floatx2 r = __builtin_amdgcn_cvt_pk_f32_fp8(v, false);
    return make_float2(r[0], r[1]);
}
__device__ __forceinline__ float2 fp8pair_hi(unsigned v) {
    floatx2 r = __builtin_amdgcn_cvt_pk_f32_fp8(v, true);
    return make_float2(r[0], r[1]);
}

// ---------- prep: W1/W2 -> fp16 MFMA B-fragments; cursor; sentinel rows ---------
// Bf1[kk(4)][ct(4)][lane(64)][8]: B[n=ct*16+(L&15)][k=kk*32+(L>>4)*8+j]
// Bf2[kk(2)][ct(3)][lane(64)][8]: cols >= 40 zero-padded
__global__ void k_prep(const float* __restrict__ W1, const float* __restrict__ W2,
                       _Float16* __restrict__ Bf1, _Float16* __restrict__ Bf2,
                       int* __restrict__ cursor, float* __restrict__ alsrc,
                       float* __restrict__ al2s, unsigned char* __restrict__ h1,
                       __half* __restrict__ h2p) {
    int tid = blockIdx.x * 256 + threadIdx.x;
    if (tid < 1024) {
        int kk = tid >> 8, ct = (tid >> 6) & 3, L = tid & 63;
        int k0 = kk * 32 + (L >> 4) * 8, col = ct * 16 + (L & 15);
        half8 v;
        #pragma unroll
        for (int j = 0; j < 8; j++) v[j] = (_Float16)W1[(k0 + j) * 64 + col];
        *(half8*)(Bf1 + ((size_t)((kk * 4 + ct) * 64 + L)) * 8) = v;
    } else if (tid < 1024 + 384) {
        int u = tid - 1024;
        int kk = u / 192, rem = u % 192;
        int ct = rem >> 6, L = rem & 63;
        int k0 = kk * 32 + (L >> 4) * 8, col = ct * 16 + (L & 15);
        half8 v;
        #pragma unroll
        for (int j = 0; j < 8; j++)
            v[j] = (col < 40) ? (_Float16)W2[(k0 + j) * 40 + col] : (_Float16)0.f;
        *(half8*)(Bf2 + ((size_t)((kk * 3 + ct) * 64 + L)) * 8) = v;
    } else {
        int u = tid - 1408;
        if (u < NBUCK) cursor[u] = 0;
        if (u >= 200 && u < 208) alsrc[(size_t)NN * 8 + (u - 200)] = -1e30f;
        if (u == 208) al2s[NN] = -1e30f;
        if (u >= 224 && u < 240) ((unsigned*)(h1 + (size_t)NN * 64))[u - 224] = 0u;
        if (u >= 240 && u < 272) ((unsigned*)(h2p + (size_t)NN * 64))[u - 240] = 0u;
    }
}

// ---------- FUSED independent stage: blocks [0,NBA) bucketA, [NBA,NBA+NGB) gemm1
__global__ __launch_bounds__(256) void k_fusedAG(
    const int* __restrict__ ei, int* __restrict__ cursor,
    unsigned* __restrict__ bucketData,
    const float* __restrict__ x, const float* __restrict__ topo,
    const _Float16* __restrict__ Bf1,
    const float* __restrict__ a_src, const float* __restrict__ a_dst,
    unsigned char* __restrict__ h1, float* __restrict__ alsrc, float* __restrict__ aldst) {
    if (blockIdx.x < NBA) {
        __shared__ int cnt[NBUCK], base[NBUCK];
        int t = threadIdx.x;
        for (int i = t; i < NBUCK; i += 256) cnt[i] = 0;
        __syncthreads();
        int e0 = blockIdx.x * TILEA;
        int nE = min(TILEA, EE - e0);
        unsigned pk[8]; int bk[8], rk[8];
        int m = 0;
        for (int i = t; i < nE; i += 256) {
            int e = e0 + i;
            int s = ei[e], d = ei[EE + e];
            pk[m] = ((unsigned)d << 16) | (unsigned)s;
            bk[m] = d >> 8;
            rk[m] = atomicAdd(&cnt[bk[m]], 1);
            m++;
        }
        __syncthreads();
        for (int i = t; i < NBUCK; i += 256)
            base[i] = (cnt[i] > 0) ? atomicAdd(&cursor[i], cnt[i]) : 0;
        __syncthreads();
        for (int k = 0; k < m; k++) {
            int pos = base[bk[k]] + rk[k];
            if (pos < CAP) bucketData[(size_t)bk[k] * CAP + pos] = pk[k];
        }
        return;
    }
    // ---- gemm1: MFMA h1(fp8 e4m3) = [x|topo] @ W1 + attention logits (fp32)
    int wave = threadIdx.x >> 6, lane = threadIdx.x & 63;
    int row0 = (blockIdx.x - NBA) * 64 + wave * 16;
    if (row0 >= NN) return;
    int g = lane >> 4, li = lane & 15;
    int myrow = row0 + li;                        // A-operand row (m = lane&15)
    half8 B[16];
    const half8* bp = (const half8*)Bf1;
    #pragma unroll
    for (int i = 0; i < 16; i++) B[i] = bp[i * 64 + lane];
    floatx4 acc[4] = {{0,0,0,0},{0,0,0,0},{0,0,0,0},{0,0,0,0}};
    #pragma unroll
    for (int kk = 0; kk < 4; kk++) {
        int k0 = kk * 32 + g * 8;
        const float* sp = (k0 == 120) ? (topo + (size_t)myrow * 8)
                                      : (x + (size_t)myrow * 120 + k0);
        float4 u0 = ((const float4*)sp)[0];
        float4 u1 = ((const float4*)sp)[1];
        half8 av;
        av[0] = (_Float16)u0.x; av[1] = (_Float16)u0.y;
        av[2] = (_Float16)u0.z; av[3] = (_Float16)u0.w;
        av[4] = (_Float16)u1.x; av[5] = (_Float16)u1.y;
        av[6] = (_Float16)u1.z; av[7] = (_Float16)u1.w;
        #pragma unroll
        for (int ct = 0; ct < 4; ct++)
            acc[ct] = __builtin_amdgcn_mfma_f32_16x16x32_f16(av, B[kk * 4 + ct], acc[ct], 0, 0, 0);
    }
    // C layout: col = ct*16+li, row = row0 + 4*g + r
    #pragma unroll
    for (int ct = 0; ct < 4; ct++)
        #pragma unroll
        for (int r = 0; r < 4; r++)
            h1[(size_t)(row0 + 4 * g + r) * 64 + ct * 16 + li] = f32_to_fp8(acc[ct][r]);
    // attention logits: head = 2*ct + (li>>3), dim = li&7 (heads are 8-col aligned)
    float ps[4][4], pd[4][4];
    #pragma unroll
    for (int ct = 0; ct < 4; ct++) {
        int head = 2 * ct + (li >> 3), dix = li & 7;
        float asv = a_src[head * 8 + dix];
        float adv = a_dst[head * 8 + dix];
        #pragma unroll
        for (int r = 0; r < 4; r++) {
            ps[ct][r] = acc[ct][r] * asv;
            pd[ct][r] = acc[ct][r] * adv;
        }
    }
    #pragma unroll
    for (int off = 1; off <= 4; off <<= 1)
        #pragma unroll
        for (int ct = 0; ct < 4; ct++)
            #pragma unroll
            for (int r = 0; r < 4; r++) {
                ps[ct][r] += __shfl_xor(ps[ct][r], off, 64);
                pd[ct][r] += __shfl_xor(pd[ct][r], off, 64);
            }
    if ((li & 7) == 0) {
        #pragma unroll
        for (int ct = 0; ct < 4; ct++) {
            int head = 2 * ct + (li >> 3);
            #pragma unroll
            for (int r = 0; r < 4; r++) {
                int row = row0 + 4 * g + r;
                alsrc[row * 8 + head] = ps[ct][r];
                aldst[row * 8 + head] = pd[ct][r];
            }
        }
    }
}

// ---------- Pass B (1024 threads): inline arena scan + per-bucket counting sort -
__global__ __launch_bounds__(1024) void k_bucketB(const unsigned* __restrict__ bucketData,
        const int* __restrict__ cursor,
        int2* __restrict__ rowseg, int* __restrict__ srcs) {
    __shared__ int cnt[256], cur[256], sbuf[256], svals[256];
    __shared__ int sorted[CAP + 2048];
    int b = blockIdx.x, t = threadIdx.x;
    int nloc = min(256, NN - b * 256);
    int ecnt = min(cursor[b], CAP);
    size_t inBase = (size_t)b * CAP;
    if (t < 256) {
        int vv = 0;
        if (t < NBUCK) {
            int nl = min(256, NN - t * 256);
            vv = min(cursor[t], CAP) + 8 * nl;
        }
        svals[t] = vv;
    }
    __syncthreads();
    int* a = svals; int* bb = sbuf;
    for (int off = 1; off < 256; off <<= 1) {
        if (t < 256) bb[t] = a[t] + ((t >= off) ? a[t - off] : 0);
        __syncthreads();
        int* tmp = a; a = bb; bb = tmp;
    }
    int outBase = (b == 0) ? 0 : a[b - 1];
    __syncthreads();
    if (t < 256) cnt[t] = (t < nloc) ? 1 : 0;
    __syncthreads();
    for (int i = t; i < ecnt; i += 1024) {
        unsigned u = bucketData[inBase + i];
        atomicAdd(&cnt[(u >> 16) & 255], 1);
    }
    __syncthreads();
    int cv = 0, pcv = 0;
    if (t < 256) {
        cv = cnt[t];
        pcv = (t < nloc) ? ((cv + 7) & ~7) : 0;
        sbuf[t] = pcv;
    }
    __syncthreads();
    a = sbuf; bb = cnt;
    for (int off = 1; off < 256; off <<= 1) {
        if (t < 256) bb[t] = a[t] + ((t >= off) ? a[t - off] : 0);
        __syncthreads();
        int* tmp = a; a = bb; bb = tmp;
    }
    int total = a[255];
    int excl = (t < 256) ? (a[t] - pcv) : 0;
    __syncthreads();
    if (t < nloc) {
        rowseg[b * 256 + t] = make_int2(outBase + excl, outBase + excl + pcv);
        sorted[excl] = b * 256 + t;              // self loop at slot 0 of segment
        for (int k = cv; k < pcv; k++) sorted[excl + k] = NN;  // sentinel pads
        cur[t] = excl + 1;
    }
    __syncthreads();
    for (int i = t; i < ecnt; i += 1024) {
        unsigned u = bucketData[inBase + i];
        int ld = (u >> 16) & 255;
        int p = atomicAdd(&cur[ld], 1);
        sorted[p] = (int)(u & 0xffffu);
    }
    __syncthreads();
    for (int i = t; i < total; i += 1024) srcs[outBase + i] = sorted[i];
}

// ------- layer 1 aggregation: 4 cols/lane (dword fp8), 4 edges in flight --------
__global__ __launch_bounds__(256) void k_agg1(
    const int2* __restrict__ rowseg, const int* __restrict__ srcs,
    const float* __restrict__ alsrc, const float* __restrict__ aldst,
    const unsigned char* __restrict__ h1, const float* __restrict__ b1,
    __half* __restrict__ hout) {
    int wave = threadIdx.x >> 6;
    int lane = threadIdx.x & 63;
    int d = blockIdx.x * 4 + wave;
    if (d >= NN) return;
    int eh = lane >> 4;          // edge sub-slot (4 edges in flight)
    int cq = lane & 15;          // col quad: cols 4cq..4cq+3
    int hh = cq >> 1;            // head (8 cols per head)
    float adst = aldst[d * 8 + hh];
    int2 seg = rowseg[d];
    int jb = seg.x, je = seg.y;
    float a0 = 0.f, a1 = 0.f, a2 = 0.f, a3 = 0.f, ssum = 0.f;
    int sA = srcs[jb + eh], sB = srcs[jb + 4 + eh];
    for (int j = jb; j < je; j += 8) {
        int s0 = sA, s1 = sB;
        int jn = j + 8;
        if (jn < je) {           // wave-uniform branch
            sA = srcs[jn + eh]; sB = srcs[jn + 4 + eh];
        }
        float e0 = alsrc[s0 * 8 + hh] + adst;
        float e1 = alsrc[s1 * 8 + hh] + adst;
        unsigned q0 = *(const unsigned*)(h1 + (size_t)s0 * 64 + 4 * cq);
        unsigned q1 = *(const unsigned*)(h1 + (size_t)s1 * 64 + 4 * cq);
        float p0 = __expf(fmaxf(e0, 0.2f * e0));
        float p1 = __expf(fmaxf(e1, 0.2f * e1));
        float2 f0l = fp8pair_lo(q0), f0h = fp8pair_hi(q0);
        float2 f1l = fp8pair_lo(q1), f1h = fp8pair_hi(q1);
        ssum += p0 + p1;
        a0 += p0 * f0l.x + p1 * f1l.x;
        a1 += p0 * f0l.y + p1 * f1l.y;
        a2 += p0 * f0h.x + p1 * f1h.x;
        a3 += p0 * f0h.y + p1 * f1h.y;
    }
    a0 += __shfl_xor(a0, 16, 64); a0 += __shfl_xor(a0, 32, 64);
    a1 += __shfl_xor(a1, 16, 64); a1 += __shfl_xor(a1, 32, 64);
    a2 += __shfl_xor(a2, 16, 64); a2 += __shfl_xor(a2, 32, 64);
    a3 += __shfl_xor(a3, 16, 64); a3 += __shfl_xor(a3, 32, 64);
    ssum += __shfl_xor(ssum, 16, 64); ssum += __shfl_xor(ssum, 32, 64);
    if (eh == 0) {
        float4 bv = ((const float4*)b1)[cq];
        float inv = 1.f / ssum;
        float v0 = a0 * inv + bv.x;
        float v1 = a1 * inv + bv.y;
        float v2 = a2 * inv + bv.z;
        float v3 = a3 * inv + bv.w;
        v0 = (v0 > 0.f) ? v0 : (__expf(v0) - 1.f);   // ELU
        v1 = (v1 > 0.f) ? v1 : (__expf(v1) - 1.f);
        v2 = (v2 > 0.f) ? v2 : (__expf(v2) - 1.f);
        v3 = (v3 > 0.f) ? v3 : (__expf(v3) - 1.f);
        __half2 h01 = __floats2half2_rn(v0, v1);
        __half2 h23 = __floats2half2_rn(v2, v3);
        uint2 pk;
        pk.x = *(unsigned*)&h01; pk.y = *(unsigned*)&h23;
        *(uint2*)(hout + (size_t)d * 64 + 4 * cq) = pk;
    }
}

// ------- layer 2 node GEMM via MFMA (h2p fp16, 64-col padded rows) --------------
__global__ __launch_bounds__(256) void k_gemm2(
    const __half* __restrict__ hout, const _Float16* __restrict__ Bf2,
    const float* __restrict__ a_src2, const float* __restrict__ a_dst2,
    __half* __restrict__ h2p, float* __restrict__ al2s, float* __restrict__ al2d) {
    int wave = threadIdx.x >> 6, lane = threadIdx.x & 63;
    int row0 = blockIdx.x * 64 + wave * 16;
    if (row0 >= NN) return;
    int g = lane >> 4, li = lane & 15;
    int myrow = row0 + li;
    half8 B[6];
    const half8* bp = (const half8*)Bf2;
    #pragma unroll
    for (int i = 0; i < 6; i++) B[i] = bp[i * 64 + lane];
    floatx4 acc[3] = {{0,0,0,0},{0,0,0,0},{0,0,0,0}};
    #pragma unroll
    for (int kk = 0; kk < 2; kk++) {
        int k0 = kk * 32 + g * 8;
        half8 av = *(const half8*)(hout + (size_t)myrow * 64 + k0);
        #pragma unroll
        for (int ct = 0; ct < 3; ct++)
            acc[ct] = __builtin_amdgcn_mfma_f32_16x16x32_f16(av, B[kk * 3 + ct], acc[ct], 0, 0, 0);
    }
    float ts[4] = {0.f, 0.f, 0.f, 0.f}, td[4] = {0.f, 0.f, 0.f, 0.f};
    #pragma unroll
    for (int ct = 0; ct < 3; ct++) {
        int col = ct * 16 + li;
        bool ok = (col < 40);
        float asv = ok ? a_src2[col] : 0.f;
        float adv = ok ? a_dst2[col] : 0.f;
        #pragma unroll
        for (int r = 0; r < 4; r++) {
            ts[r] += acc[ct][r] * asv;
            td[r] += acc[ct][r] * adv;
            h2p[(size_t)(row0 + 4 * g + r) * 64 + col] = __float2half(ok ? acc[ct][r] : 0.f);
        }
    }
    #pragma unroll
    for (int r = 0; r < 4; r++)   // zero-fill pad cols 48..63
        h2p[(size_t)(row0 + 4 * g + r) * 64 + 48 + li] = (__half)0.f;
    #pragma unroll
    for (int off = 1; off <= 8; off <<= 1)
        #pragma unroll
        for (int r = 0; r < 4; r++) {
            ts[r] += __shfl_xor(ts[r], off, 64);
            td[r] += __shfl_xor(td[r], off, 64);
        }
    if (li == 0) {
        #pragma unroll
        for (int r = 0; r < 4; r++) {
            int row = row0 + 4 * g + r;
            al2s[row] = ts[r];
            al2d[row] = td[r];
        }
    }
}

// ------- layer 2 aggregation + log_softmax: 4 cols/lane, 4 edges in flight ------
__global__ __launch_bounds__(256) void k_agg2(
    const int2* __restrict__ rowseg, const int* __restrict__ srcs,
    const float* __restrict__ al2s, const float* __restrict__ al2d,
    const __half* __restrict__ h2p, const float* __restrict__ b2,
    float* __restrict__ out) {
    int wave = threadIdx.x >> 6;
    int lane = threadIdx.x & 63;
    int d = blockIdx.x * 4 + wave;
    if (d >= NN) return;
    int eh = lane >> 4;
    int cq = lane & 15;              // cols 4cq..4cq+3; valid iff cq<10
    bool act = (cq < 10);
    float adst = al2d[d];
    int2 seg = rowseg[d];
    int jb = seg.x, je = seg.y;
    float a0 = 0.f, a1 = 0.f, a2 = 0.f, a3 = 0.f, ssum = 0.f;
    int sA = srcs[jb + eh], sB = srcs[jb + 4 + eh];
    for (int j = jb; j < je; j += 8) {
        int s0 = sA, s1 = sB;
        int jn = j + 8;
        if (jn < je) {
            sA = srcs[jn + eh]; sB = srcs[jn + 4 + eh];
        }
        float e0 = al2s[s0] + adst;
        float e1 = al2s[s1] + adst;
        uint2 q0 = *(const uint2*)(h2p + (size_t)s0 * 64 + 4 * cq);
        uint2 q1 = *(const uint2*)(h2p + (size_t)s1 * 64 + 4 * cq);
        float p0 = __expf(fmaxf(e0, 0.2f * e0));
        float p1 = __expf(fmaxf(e1, 0.2f * e1));
        float2 f0l = __half22float2(*(__half2*)&q0.x);
        float2 f0h = __half22float2(*(__half2*)&q0.y);
        float2 f1l = __half22float2(*(__half2*)&q1.x);
        float2 f1h = __half22float2(*(__half2*)&q1.y);
        ssum += p0 + p1;
        a0 += p0 * f0l.x + p1 * f1l.x;
        a1 += p0 * f0l.y + p1 * f1l.y;
        a2 += p0 * f0h.x + p1 * f1h.x;
        a3 += p0 * f0h.y + p1 * f1h.y;
    }
    a0 += __shfl_xor(a0, 16, 64); a0 += __shfl_xor(a0, 32, 64);
    a1 += __shfl_xor(a1, 16, 64); a1 += __shfl_xor(a1, 32, 64);
    a2 += __shfl_xor(a2, 16, 64); a2 += __shfl_xor(a2, 32, 64);
    a3 += __shfl_xor(a3, 16, 64); a3 += __shfl_xor(a3, 32, 64);
    ssum += __shfl_xor(ssum, 16, 64); ssum += __shfl_xor(ssum, 32, 64);
    float inv = 1.f / ssum;
    float4 bv = act ? ((const float4*)b2)[cq] : make_float4(0.f, 0.f, 0.f, 0.f);
    float o0 = a0 * inv + bv.x;
    float o1 = a1 * inv + bv.y;
    float o2 = a2 * inv + bv.z;
    float o3 = a3 * inv + bv.w;
    float mo = act ? fmaxf(fmaxf(o0, o1), fmaxf(o2, o3)) : -3.0e38f;
    #pragma unroll
    for (int off = 1; off <= 8; off <<= 1) mo = fmaxf(mo, __shfl_xor(mo, off, 64));
    float te = act ? (__expf(o0 - mo) + __expf(o1 - mo) + __expf(o2 - mo) + __expf(o3 - mo)) : 0.f;
    #pragma unroll
    for (int off = 1; off <= 8; off <<= 1) te += __shfl_xor(te, off, 64);
    float ls = __logf(te);
    if (act && eh == 0) {
        float4 ov = make_float4(o0 - mo - ls, o1 - mo - ls, o2 - mo - ls, o3 - mo - ls);
        *(float4*)(out + (size_t)d * 40 + 4 * cq) = ov;
    }
}

extern "C" void kernel_launch(void* const* d_in, const int* in_sizes, int n_in,
                              void* d_out, int out_size, void* d_ws, size_t ws_size,
                              hipStream_t stream) {
    (void)in_sizes; (void)n_in; (void)out_size; (void)ws_size;
    const float* x    = (const float*)d_in[0];
    const float* topo = (const float*)d_in[1];
    const int*   ei   = (const int*)d_in[2];
    const float* W1   = (const float*)d_in[3];
    const float* as1  = (const float*)d_in[4];
    const float* ad1  = (const float*)d_in[5];
    const float* b1   = (const float*)d_in[6];
    const float* W2   = (const float*)d_in[7];
    const float* as2  = (const float*)d_in[8];
    const float* ad2  = (const float*)d_in[9];
    const float* b2   = (const float*)d_in[10];
    float* out = (float*)d_out;

    char* ws = (char*)d_ws;
    size_t off = 0;
    auto alloc = [&](size_t bytes) {
        void* p = ws + off;
        off += (bytes + 255) / 256 * 256;
        return p;
    };
    int2*          rowseg     = (int2*)alloc((size_t)NN * 8);
    int*           cursor     = (int*)alloc(NBUCK * 4);
    unsigned*      bucketData = (unsigned*)alloc((size_t)NBUCK * CAP * 4);
    int*           srcs       = (int*)alloc((size_t)SRCS_MAX * 4);
    float*         alsrc1     = (float*)alloc((size_t)(NN + 1) * 8 * 4);
    float*         aldst1     = (float*)alloc((size_t)NN * 8 * 4);
    float*         al2s       = (float*)alloc((NN + 1) * 4);
    float*         al2d       = (float*)alloc(NN * 4);
    _Float16*      Bf1        = (_Float16*)alloc(4 * 4 * 64 * 8 * 2);
    _Float16*      Bf2        = (_Float16*)alloc(2 * 3 * 64 * 8 * 2);
    unsigned char* h1         = (unsigned char*)alloc((size_t)(NN + 1) * 64);
    __half*        hout       = (__half*)alloc((size_t)NN * 64 * 2);
    __half*        h2p        = (__half*)alloc((size_t)(NN + 1) * 64 * 2);

    k_prep    <<<7,         256,  0, stream>>>(W1, W2, Bf1, Bf2, cursor, alsrc1, al2s, h1, h2p);
    k_fusedAG <<<NBA + NGB, 256,  0, stream>>>(ei, cursor, bucketData,
                                               x, topo, Bf1, as1, ad1, h1, alsrc1, aldst1);
    k_bucketB <<<NBUCK,     1024, 0, stream>>>(bucketData, cursor, rowseg, srcs);
    k_agg1    <<<(NN + 3) / 4, 256, 0, stream>>>(rowseg, srcs, alsrc1, aldst1, h1, b1, hout);
    k_gemm2   <<<782,       256,  0, stream>>>(hout, Bf2, as2, ad2, h2p, al2s, al2d);
    k_agg2    <<<(NN + 3) / 4, 256, 0, stream>>>(rowseg, srcs, al2s, al2d, h2p, b2, out);
}